// Round 12
// baseline (2313.250 us; speedup 1.0000x reference)
//
#include <hip/hip_runtime.h>
#include <hip/hip_bf16.h>

#define B_ 2
#define S_ 2048
#define H_ 768
#define NH_ 12
#define HD_ 64
#define L_ 6
#define I_ 3072
#define M_ 256
#define BS_ 4096           // B*S
#define R_ 49152           // B*S*NH
#define NXH_ 3145728       // BS*H
#define EPS_ 1e-6f
#define DN_ 0.35355339059327373f   // 1/sqrt(sqrt(64))
#define RATIO_ 0.0625f             // 1/sqrt(256)

typedef __attribute__((ext_vector_type(8))) short bf16x8;
typedef __attribute__((ext_vector_type(4))) float f32x4;

__device__ __forceinline__ void gload16(const void* g, void* l) {
    __builtin_amdgcn_global_load_lds(
        (const __attribute__((address_space(1))) void*)g,
        (__attribute__((address_space(3))) void*)l, 16, 0, 0);
}

__device__ __forceinline__ float gelu_f(float x) {
    const float c = 0.7978845608028654f;
    float x3 = x * x * x;
    return 0.5f * x * (1.0f + tanhf(c * (x + 0.044715f * x3)));
}

// monotone float<->uint encoding for atomicMax on floats (exact, order-independent)
__device__ __forceinline__ unsigned enc_f(float f) {
    unsigned u = __float_as_uint(f);
    return (u & 0x80000000u) ? ~u : (u | 0x80000000u);
}
__device__ __forceinline__ float dec_f(unsigned u) {
    return (u & 0x80000000u) ? __uint_as_float(u & 0x7fffffffu) : __uint_as_float(~u);
}

__device__ __forceinline__ void blockReduceSum2(float& a, float& b) {
    __shared__ float sa[4], sb[4];
    int lane = threadIdx.x & 63, wid = threadIdx.x >> 6;
    #pragma unroll
    for (int off = 32; off; off >>= 1) {
        a += __shfl_down(a, off, 64);
        b += __shfl_down(b, off, 64);
    }
    __syncthreads();
    if (lane == 0) { sa[wid] = a; sb[wid] = b; }
    __syncthreads();
    a = sa[0] + sa[1] + sa[2] + sa[3];
    b = sb[0] + sb[1] + sb[2] + sb[3];
    __syncthreads();
}

// ============== gemm_pipe3w: 256x128 tile, 4 waves (wave tile 128x64 = 32 MFMA/step),
// BK=32, depth-3 LDS ring (72 KB, 2 blocks/CU), counted vmcnt (6 loads/iter -> 12/6/0),
// own-wave vmcnt BEFORE rendezvous barrier, two raw barriers/iter, setprio, chunk-XOR swizzle.
// OUTMODE: 1 = bf16 out (+ACT gelu), 2 = QKV split bf16 + fused qd/kd,
//          3 = split-K fp32 plane (aux + blockIdx.z*NXH_)
template<int ACT, int OUTMODE>
__global__ __launch_bounds__(256) void gemm_pipe3w_kernel(
    const __hip_bfloat16* __restrict__ A, const __hip_bfloat16* __restrict__ BT,
    const float* __restrict__ bias, void* __restrict__ Cv,
    int K, int lda, int ldb, int ldc, float* __restrict__ aux)
{
    __shared__ __align__(16) unsigned short As[3][256][32];   // 48 KB
    __shared__ __align__(16) unsigned short Bs[3][128][32];   // 24 KB
    const int tid = threadIdx.x, lane = tid & 63, wid = tid >> 6;
    const int wr = wid >> 1, wc = wid & 1;
    const size_t r0 = (size_t)blockIdx.y * 256;
    const int n0 = blockIdx.x * 128;
    const size_t kbase = (size_t)blockIdx.z * (size_t)K;

    const int srow = lane >> 2;
    const int selem = ((lane & 3) ^ ((srow >> 1) & 3)) * 8;   // pre-swizzled source chunk
    const unsigned short* ga0 = (const unsigned short*)A + (r0 + wid * 64 + srow) * (size_t)lda + kbase + selem;
    const unsigned short* gb0 = (const unsigned short*)BT + ((size_t)n0 + wid * 32 + srow) * (size_t)ldb + kbase + selem;

    f32x4 acc[8][4];
    #pragma unroll
    for (int i = 0; i < 8; i++)
        #pragma unroll
        for (int j = 0; j < 4; j++)
            acc[i][j] = (f32x4){0.f, 0.f, 0.f, 0.f};

    const int lr = lane & 15;
    const int rc8 = (((lane >> 4) ^ ((lr >> 1) & 3))) * 8;    // swizzled read chunk

#define STAGE_(t) { const int bb_ = (t) % 3; const int kk_ = (t) * 32;            \
    gload16(ga0 + kk_,                      &As[bb_][wid * 64][0]);               \
    gload16(ga0 + kk_ + 16 * (size_t)lda,   &As[bb_][wid * 64 + 16][0]);          \
    gload16(ga0 + kk_ + 32 * (size_t)lda,   &As[bb_][wid * 64 + 32][0]);          \
    gload16(ga0 + kk_ + 48 * (size_t)lda,   &As[bb_][wid * 64 + 48][0]);          \
    gload16(gb0 + kk_,                      &Bs[bb_][wid * 32][0]);               \
    gload16(gb0 + kk_ + 16 * (size_t)ldb,   &Bs[bb_][wid * 32 + 16][0]); }

#define ITER_(t, VMSTR, DOSTAGE) {                                                \
    if (DOSTAGE) STAGE_((t) + 2);                                                 \
    asm volatile("s_waitcnt vmcnt(" VMSTR ")" ::: "memory");                      \
    __builtin_amdgcn_sched_barrier(0);                                            \
    __builtin_amdgcn_s_barrier();                                                 \
    __builtin_amdgcn_sched_barrier(0);                                            \
    const int bb_ = (t) % 3;                                                      \
    bf16x8 bfv[4];                                                                \
    _Pragma("unroll") for (int j = 0; j < 4; j++)                                 \
        bfv[j] = *(const bf16x8*)&Bs[bb_][wc * 64 + j * 16 + lr][rc8];            \
    _Pragma("unroll") for (int ih = 0; ih < 2; ih++) {                            \
        bf16x8 af[4];                                                             \
        _Pragma("unroll") for (int i = 0; i < 4; i++)                             \
            af[i] = *(const bf16x8*)&As[bb_][wr * 128 + (ih * 4 + i) * 16 + lr][rc8]; \
        __builtin_amdgcn_s_setprio(1);                                            \
        _Pragma("unroll") for (int i = 0; i < 4; i++)                             \
            _Pragma("unroll") for (int j = 0; j < 4; j++)                         \
                acc[ih * 4 + i][j] = __builtin_amdgcn_mfma_f32_16x16x32_bf16(af[i], bfv[j], acc[ih * 4 + i][j], 0, 0, 0); \
        __builtin_amdgcn_s_setprio(0);                                            \
    }                                                                             \
    __builtin_amdgcn_s_barrier();                                                 \
    __builtin_amdgcn_sched_barrier(0); }

    const int nT = K >> 5;
    STAGE_(0); STAGE_(1);
    for (int t = 0; t < nT - 2; ++t) ITER_(t, "12", true);
    ITER_(nT - 2, "6", false);
    ITER_(nT - 1, "0", false);
#undef ITER_
#undef STAGE_

    const int rr = (lane >> 4) * 4;
    const int cc = lane & 15;
    if (OUTMODE == 3) {
        float* fpl = aux + (size_t)blockIdx.z * NXH_;
        #pragma unroll
        for (int i = 0; i < 8; i++) {
            #pragma unroll
            for (int j = 0; j < 4; j++) {
                size_t col = (size_t)n0 + wc * 64 + j * 16 + cc;
                #pragma unroll
                for (int rg = 0; rg < 4; rg++) {
                    size_t row = r0 + wr * 128 + i * 16 + rr + rg;
                    fpl[row * (size_t)ldc + col] = acc[i][j][rg];
                }
            }
        }
    } else if (OUTMODE == 1) {
        #pragma unroll
        for (int i = 0; i < 8; i++) {
            #pragma unroll
            for (int j = 0; j < 4; j++) {
                size_t col = (size_t)n0 + wc * 64 + j * 16 + cc;
                float bv_ = bias ? bias[col] : 0.f;
                #pragma unroll
                for (int rg = 0; rg < 4; rg++) {
                    size_t row = r0 + wr * 128 + i * 16 + rr + rg;
                    float v = acc[i][j][rg] + bv_;
                    if (ACT == 1) v = gelu_f(v);
                    ((__hip_bfloat16*)Cv)[row * (size_t)ldc + col] = __float2bfloat16(v);
                }
            }
        }
    } else {  // OUTMODE 2: QKV split + fused qd/kd (wave's 64 cols = one head)
        const size_t seg = (size_t)n0 / 768;
        const int colbase = n0 - (int)seg * 768;
        #pragma unroll
        for (int i = 0; i < 8; i++) {
            #pragma unroll
            for (int rg = 0; rg < 4; rg++) {
                size_t row = r0 + wr * 128 + i * 16 + rr + rg;
                float ss = 0.f;
                #pragma unroll
                for (int j = 0; j < 4; j++) {
                    int colw = wc * 64 + j * 16 + cc;
                    size_t col = (size_t)n0 + colw;
                    float bv_ = bias ? bias[col] : 0.f;
                    float v = acc[i][j][rg] + bv_;
                    __hip_bfloat16 hb = __float2bfloat16(v);
                    ((__hip_bfloat16*)Cv)[seg * (size_t)NXH_ + row * 768 + colbase + colw] = hb;
                    float vr = __bfloat162float(hb);
                    ss += vr * vr;
                }
                #pragma unroll
                for (int off = 1; off <= 8; off <<= 1)
                    ss += __shfl_xor(ss, off, 64);
                if (seg < 2 && (lane & 15) == 0) {
                    int nh = colbase / 64 + wc;
                    aux[seg * (size_t)R_ + row * 12 + nh] = 0.5f * DN_ * DN_ * ss;
                }
            }
        }
    }
}

// ============== gemm_pipe3_n64: 128x64 tile, depth-3 ring (36 KB), fp32 out + bias.
__global__ __launch_bounds__(256) void gemm_pipe3_n64_kernel(
    const __hip_bfloat16* __restrict__ A, const __hip_bfloat16* __restrict__ BT,
    const float* __restrict__ bias, float* __restrict__ C,
    int K, int lda, int ldb, int ldc)
{
    __shared__ __align__(16) unsigned short As[3][128][32];   // 24 KB
    __shared__ __align__(16) unsigned short Bs[3][64][32];    // 12 KB
    const int tid = threadIdx.x, lane = tid & 63, wid = tid >> 6;
    const size_t r0 = (size_t)blockIdx.y * 128;
    const int n0 = blockIdx.x * 64;

    const int srow = lane >> 2;
    const int selem = ((lane & 3) ^ ((srow >> 1) & 3)) * 8;
    const unsigned short* ga0 = (const unsigned short*)A + (r0 + wid * 32 + srow) * (size_t)lda + selem;
    const unsigned short* gb0 = (const unsigned short*)BT + ((size_t)n0 + wid * 16 + srow) * (size_t)ldb + selem;

    f32x4 acc[2][4];
    #pragma unroll
    for (int i = 0; i < 2; i++)
        #pragma unroll
        for (int j = 0; j < 4; j++)
            acc[i][j] = (f32x4){0.f, 0.f, 0.f, 0.f};

    const int lr = lane & 15;
    const int rc8 = (((lane >> 4) ^ ((lr >> 1) & 3))) * 8;

#define STAGE_(t) { const int bb_ = (t) % 3; const int kk_ = (t) * 32;            \
    gload16(ga0 + kk_, &As[bb_][wid * 32][0]);                                    \
    gload16(ga0 + kk_ + 16 * (size_t)lda, &As[bb_][wid * 32 + 16][0]);            \
    gload16(gb0 + kk_, &Bs[bb_][wid * 16][0]); }

#define ITER_(t, VMSTR, DOSTAGE) {                                                \
    if (DOSTAGE) STAGE_((t) + 2);                                                 \
    asm volatile("s_waitcnt vmcnt(" VMSTR ")" ::: "memory");                      \
    __builtin_amdgcn_sched_barrier(0);                                            \
    __builtin_amdgcn_s_barrier();                                                 \
    __builtin_amdgcn_sched_barrier(0);                                            \
    const int bb_ = (t) % 3;                                                      \
    bf16x8 af[2], bfv[4];                                                         \
    _Pragma("unroll") for (int i = 0; i < 2; i++)                                 \
        af[i] = *(const bf16x8*)&As[bb_][wid * 32 + i * 16 + lr][rc8];            \
    _Pragma("unroll") for (int j = 0; j < 4; j++)                                 \
        bfv[j] = *(const bf16x8*)&Bs[bb_][j * 16 + lr][rc8];                      \
    __builtin_amdgcn_s_setprio(1);                                                \
    _Pragma("unroll") for (int i = 0; i < 2; i++)                                 \
        _Pragma("unroll") for (int j = 0; j < 4; j++)                             \
            acc[i][j] = __builtin_amdgcn_mfma_f32_16x16x32_bf16(af[i], bfv[j], acc[i][j], 0, 0, 0); \
    __builtin_amdgcn_s_setprio(0);                                                \
    __builtin_amdgcn_s_barrier();                                                 \
    __builtin_amdgcn_sched_barrier(0); }

    const int nT = K >> 5;
    STAGE_(0); STAGE_(1);
    for (int t = 0; t < nT - 2; ++t) ITER_(t, "6", true);
    ITER_(nT - 2, "3", false);
    ITER_(nT - 1, "0", false);
#undef ITER_
#undef STAGE_

    const int rr = (lane >> 4) * 4, cc = lane & 15;
    #pragma unroll
    for (int i = 0; i < 2; i++) {
        #pragma unroll
        for (int j = 0; j < 4; j++) {
            int col = n0 + j * 16 + cc;
            float bv_ = bias ? bias[col] : 0.f;
            #pragma unroll
            for (int rg = 0; rg < 4; rg++) {
                size_t row = r0 + wid * 32 + i * 16 + rr + rg;
                C[row * (size_t)ldc + col] = acc[i][j][rg] + bv_;
            }
        }
    }
}

// ---------------- proj-K: 128x128 tile, 2-phase dbuf, bf16 C out + atomic global max
__global__ __launch_bounds__(256) void gemm_projk_kernel(
    const __hip_bfloat16* __restrict__ A, const __hip_bfloat16* __restrict__ BT,
    __hip_bfloat16* __restrict__ Cv,
    int K, int lda, int ldb, int ldc, float alpha,
    unsigned* __restrict__ gmaxu)
{
    __shared__ __align__(16) unsigned short As[2][128][32];
    __shared__ __align__(16) unsigned short Bs[2][128][32];
    __shared__ float rmx[128][2];
    __shared__ float rowm[128];
    const int tid = threadIdx.x, lane = tid & 63, wid = tid >> 6;
    const int wr = wid >> 1, wc = wid & 1;
    const size_t r0 = (size_t)blockIdx.y * 128;
    const int n0 = blockIdx.x * 128;

    const int srow = lane >> 2;
    const int selem = ((lane & 3) ^ ((srow >> 1) & 3)) * 8;
    const unsigned short* ga0 = (const unsigned short*)A + (r0 + wid * 32 + srow) * (size_t)lda + selem;
    const unsigned short* gb0 = (const unsigned short*)BT + ((size_t)n0 + wid * 32 + srow) * (size_t)ldb + selem;

    f32x4 acc[4][4];
    #pragma unroll
    for (int i = 0; i < 4; i++)
        #pragma unroll
        for (int j = 0; j < 4; j++)
            acc[i][j] = (f32x4){0.f, 0.f, 0.f, 0.f};

    gload16(ga0, &As[0][wid * 32][0]);
    gload16(ga0 + 16 * (size_t)lda, &As[0][wid * 32 + 16][0]);
    gload16(gb0, &Bs[0][wid * 32][0]);
    gload16(gb0 + 16 * (size_t)ldb, &Bs[0][wid * 32 + 16][0]);
    __syncthreads();

    const int lr = lane & 15;
    const int rc8 = (((lane >> 4) ^ ((lr >> 1) & 3))) * 8;

    int cur = 0;
    for (int k0 = 0; k0 < K; k0 += 32) {
        const int kn = k0 + 32;
        if (kn < K) {
            gload16(ga0 + kn, &As[cur ^ 1][wid * 32][0]);
            gload16(ga0 + kn + 16 * (size_t)lda, &As[cur ^ 1][wid * 32 + 16][0]);
            gload16(gb0 + kn, &Bs[cur ^ 1][wid * 32][0]);
            gload16(gb0 + kn + 16 * (size_t)ldb, &Bs[cur ^ 1][wid * 32 + 16][0]);
        }
        bf16x8 af[4], bfv[4];
        #pragma unroll
        for (int i = 0; i < 4; i++)
            af[i] = *(const bf16x8*)&As[cur][wr * 64 + i * 16 + lr][rc8];
        #pragma unroll
        for (int j = 0; j < 4; j++)
            bfv[j] = *(const bf16x8*)&Bs[cur][wc * 64 + j * 16 + lr][rc8];
        #pragma unroll
        for (int i = 0; i < 4; i++)
            #pragma unroll
            for (int j = 0; j < 4; j++)
                acc[i][j] = __builtin_amdgcn_mfma_f32_16x16x32_bf16(af[i], bfv[j], acc[i][j], 0, 0, 0);
        __syncthreads();
        cur ^= 1;
    }

    const int rr = (lane >> 4) * 4;
    const int cc = lane & 15;
    #pragma unroll
    for (int i = 0; i < 4; i++) {
        #pragma unroll
        for (int j = 0; j < 4; j++) {
            int colw = wc * 64 + j * 16 + cc;
            size_t col = (size_t)n0 + colw;
            #pragma unroll
            for (int rg = 0; rg < 4; rg++) {
                size_t row = r0 + wr * 64 + i * 16 + rr + rg;
                Cv[row * ldc + col] = __float2bfloat16(acc[i][j][rg] * alpha);
            }
        }
    }
    #pragma unroll
    for (int i = 0; i < 4; i++) {
        #pragma unroll
        for (int rg = 0; rg < 4; rg++) {
            float rm = -3.4e38f;
            #pragma unroll
            for (int j = 0; j < 4; j++) rm = fmaxf(rm, acc[i][j][rg] * alpha);
            #pragma unroll
            for (int off = 1; off <= 8; off <<= 1)
                rm = fmaxf(rm, __shfl_xor(rm, off, 64));
            if ((lane & 15) == 0) rmx[wr * 64 + i * 16 + rr + rg][wc] = rm;
        }
    }
    __syncthreads();
    if (tid < 128) rowm[tid] = fmaxf(rmx[tid][0], rmx[tid][1]);
    __syncthreads();
    if (tid < 12) {
        int b = (int)(r0 / 24576);
        int h = (int)((r0 + tid) % 12);
        float m = -3.4e38f;
        for (int k = tid; k < 128; k += 12) m = fmaxf(m, rowm[k]);
        atomicMax(&gmaxu[b * 12 + h], enc_f(m));
    }
}

// ---------------- FUSED proj-Q + rowmax + q' + den + num. Grid (16, 24) x 512 thr.
__global__ __launch_bounds__(512) void qnum_fused_kernel(
    const __hip_bfloat16* __restrict__ Qbp, const __hip_bfloat16* __restrict__ projb,
    const float* __restrict__ qd, const float* __restrict__ ksum,
    const __hip_bfloat16* __restrict__ kvT, __hip_bfloat16* __restrict__ ATT)
{
    __shared__ __align__(16) unsigned short Pl[128][256];     // 64 KB (q'; overlays Asm/Bsm)
    __shared__ __align__(16) unsigned short kvTl[64][256];    // 32 KB
    __shared__ float ksl[256];
    __shared__ float qdl[128];
    __shared__ float red[128][4];
    __shared__ float rmaxv[128];
    __shared__ float deni[128];
    unsigned short (*Asm)[64] = (unsigned short (*)[64])&Pl[0][0];            // [128][64]
    unsigned short (*Bsm)[64] = (unsigned short (*)[64])(&Pl[0][0] + 8192);   // [256][64]

    const int tid = threadIdx.x, lane = tid & 63, w = tid >> 6;
    const int wrow = w >> 2, wcol = w & 3;
    const int bn = blockIdx.y, b = bn / NH_, n = bn % NH_;
    const size_t r0g = (size_t)b * S_ + (size_t)blockIdx.x * 128;

    if (tid < 256) ksl[tid] = ksum[(size_t)bn * 256 + tid];
    else if (tid < 384) qdl[tid - 256] = qd[(r0g + tid - 256) * 12 + n];

    const int lrow = lane >> 3, lch = lane & 7;
    const int sch = (lch ^ (lrow & 7)) * 8;
    gload16((const unsigned short*)Qbp + (r0g + w * 16 + lrow) * 768 + n * 64 + sch, &Asm[w * 16][0]);
    gload16((const unsigned short*)Qbp + (r0g + w * 16 + 8 + lrow) * 768 + n * 64 + sch, &Asm[w * 16 + 8][0]);
    #pragma unroll
    for (int p = 0; p < 4; p++)
        gload16((const unsigned short*)projb + (size_t)(w * 32 + p * 8 + lrow) * 64 + sch,
                &Bsm[w * 32 + p * 8][0]);
    {
        const int rIn = lane >> 5, c32 = lane & 31;
        #pragma unroll
        for (int p = 0; p < 4; p++) {
            int d = w * 8 + p * 2 + rIn;
            gload16((const unsigned short*)kvT + (size_t)bn * (HD_ * M_) + (size_t)d * 256
                    + (c32 ^ (d & 7)) * 8, &kvTl[w * 8 + p * 2][0]);
        }
    }
    __syncthreads();

    const int lr = lane & 15, kq = lane >> 4;
    f32x4 acc[4][4];
    #pragma unroll
    for (int i = 0; i < 4; i++)
        #pragma unroll
        for (int j = 0; j < 4; j++)
            acc[i][j] = (f32x4){0.f, 0.f, 0.f, 0.f};

    // phase 1: qp = Q . proj^T  (K=64, 2 k-steps)
    #pragma unroll
    for (int ks = 0; ks < 2; ks++) {
        const int ch = (((ks << 2) | kq) ^ (lr & 7)) * 8;
        bf16x8 af[4], bfv[4];
        #pragma unroll
        for (int i = 0; i < 4; i++)
            af[i] = *(const bf16x8*)&Asm[wrow * 64 + i * 16 + lr][ch];
        #pragma unroll
        for (int j = 0; j < 4; j++)
            bfv[j] = *(const bf16x8*)&Bsm[wcol * 64 + j * 16 + lr][ch];
        #pragma unroll
        for (int i = 0; i < 4; i++)
            #pragma unroll
            for (int j = 0; j < 4; j++)
                acc[i][j] = __builtin_amdgcn_mfma_f32_16x16x32_bf16(af[i], bfv[j], acc[i][j], 0, 0, 0);
    }

    // phase 2: row-max over 256 cols
    #pragma unroll
    for (int i = 0; i < 4; i++) {
        #pragma unroll
        for (int rg = 0; rg < 4; rg++) {
            float rm = -3.4e38f;
            #pragma unroll
            for (int j = 0; j < 4; j++) rm = fmaxf(rm, acc[i][j][rg] * DN_);
            #pragma unroll
            for (int off = 1; off <= 8; off <<= 1)
                rm = fmaxf(rm, __shfl_xor(rm, off, 64));
            if ((lane & 15) == 0) red[wrow * 64 + i * 16 + kq * 4 + rg][wcol] = rm;
        }
    }
    __syncthreads();
    if (tid < 128)
        rmaxv[tid] = fmaxf(fmaxf(red[tid][0], red[tid][1]), fmaxf(red[tid][2], red[tid][3]));
    __syncthreads();

    // phase 3: q' -> bf16 in LDS (swizzled) + den partials
    #pragma unroll
    for (int i = 0; i < 4; i++) {
        #pragma unroll
        for (int rg = 0; rg < 4; rg++) {
            int row = wrow * 64 + i * 16 + kq * 4 + rg;
            float qdv = qdl[row], mx = rmaxv[row];
            float dsum = 0.f;
            #pragma unroll
            for (int j = 0; j < 4; j++) {
                int col = wcol * 64 + j * 16 + lr;
                float qp = acc[i][j][rg] * DN_;
                float qv = RATIO_ * (expf(qp - qdv - mx) + EPS_);
                __hip_bfloat16 qb = __float2bfloat16(qv);
                Pl[row][((col >> 3) ^ (row & 7)) * 8 + (col & 7)] = *(unsigned short*)&qb;
                dsum += __bfloat162float(qb) * ksl[col];
            }
            #pragma unroll
            for (int off = 1; off <= 8; off <<= 1)
                dsum += __shfl_xor(dsum, off, 64);
            if ((lane & 15) == 0) red[row][wcol] = dsum;
        }
    }
    __syncthreads();
    if (tid < 128)
        deni[tid] = red[tid][0] + red[tid][1] + red[tid][2] + red[tid][3];
    __syncthreads();

    // phase 4: num = q' . kvT^T (K=256, 8 k-steps); wave w owns rows w*16..w*16+15
    f32x4 acc2[4];
    #pragma unroll
    for (int j = 0; j < 4; j++) acc2[j] = (f32x4){0.f, 0.f, 0.f, 0.f};
    #pragma unroll
    for (int ks = 0; ks < 8; ks++) {
        const int mc = ks * 4 + kq;
        const int sl = (mc ^ (lr & 7)) * 8;
        bf16x8 af = *(const bf16x8*)&Pl[w * 16 + lr][sl];
        #pragma unroll
        for (int j = 0; j < 4; j++) {
            bf16x8 bfv = *(const bf16x8*)&kvTl[j * 16 + lr][sl];
            acc2[j] = __builtin_amdgcn_mfma_f32_16x16x32_bf16(af, bfv, acc2[j], 0, 0, 0);
        }
    }
    #pragma unroll
    for (int rg = 0; rg < 4; rg++) {
        int row = w * 16 + kq * 4 + rg;
        float inv = 1.0f / deni[row];
        #pragma unroll
        for (int j = 0; j < 4; j++)
            ATT[(r0g + row) * 768 + n * 64 + j * 16 + lr]
                = __float2bfloat16(acc2[j][rg] * inv);
    }
}

// ---------------- FUSED k' + kv split-K + ksum partials. Grid (4 m0, 24 bn, 8 chunk).
__global__ __launch_bounds__(256) void kv_fused_kernel(
    const __hip_bfloat16* __restrict__ KF, const __hip_bfloat16* __restrict__ Vb,
    const float* __restrict__ kd, const unsigned* __restrict__ gmaxu,
    const int* __restrict__ amask,
    float* __restrict__ part, float* __restrict__ kpart)
{
    const int m0 = blockIdx.x * 64, bn = blockIdx.y, b = bn / NH_, n = bn % NH_;
    const int s0 = blockIdx.z * 256;
    __shared__ __align__(16) float As2[16][68];
    __shared__ __align__(16) float Bs2[16][68];
    __shared__ float sred[4][64];
    const int tid = threadIdx.x, tx = tid & 15, ty = tid >> 4;
    const float gm = dec_f(gmaxu[bn]);
    float acc[4][4] = {};
    float ks = 0.f;
    for (int ss = 0; ss < 256; ss += 16) {
        #pragma unroll
        for (int i = 0; i < 4; i++) {
            int idx = tid + i * 256;
            int kk = idx >> 6, c = idx & 63;
            size_t srow = (size_t)b * S_ + s0 + ss + kk;
            float kdv = kd[srow * 12 + n];
            float mk = (float)amask[srow];
            float kf = __bfloat162float(KF[srow * (NH_ * M_) + n * M_ + m0 + c]);
            float kp = RATIO_ * (expf(kf - kdv - gm) + EPS_) * mk;
            As2[kk][c] = kp;
            ks += kp;
            Bs2[kk][c] = __bfloat162float(Vb[srow * H_ + n * HD_ + c]);
        }
        __syncthreads();
        #pragma unroll
        for (int kk = 0; kk < 16; kk++) {
            float4 av = *reinterpret_cast<const float4*>(&As2[kk][ty * 4]);
            float4 bv = *reinterpret_cast<const float4*>(&Bs2[kk][tx * 4]);
            float a4[4] = {av.x, av.y, av.z, av.w};
            float b4[4] = {bv.x, bv.y, bv.z, bv.w};
            #pragma unroll
            for (int i = 0; i < 4; i++)
                #pragma unroll
                for (int j = 0; j < 4; j++)
                    acc[i][j] += a4[i] * b4[j];
        }
        __syncthreads();
    }
    float* Cb = part + ((size_t)blockIdx.z * (B_ * NH_) + bn) * (M_ * HD_);
    #pragma unroll
    for (int j = 0; j < 4; j++)
        #pragma unroll
        for (int i = 0; i < 4; i++)
            Cb[(size_t)(tx * 4 + j) * M_ + m0 + ty * 4 + i] = acc[i][j];
    sred[tid >> 6][tid & 63] = ks;
    __syncthreads();
    if (tid < 64)
        kpart[((size_t)bn * 8 + blockIdx.z) * M_ + m0 + tid]
            = sred[0][tid] + sred[1][tid] + sred[2][tid] + sred[3][tid];
}

// reduce 8 chunks -> kvT bf16 [bn][d][m] (d<64) OR ksum (blockIdx.y==64). Grid (24, 65).
__global__ __launch_bounds__(256) void kvred_kernel(
    const float* __restrict__ part, __hip_bfloat16* __restrict__ kvT,
    const float* __restrict__ kpart, float* __restrict__ ksum)
{
    const int bn = blockIdx.x, d = blockIdx.y, m = threadIdx.x;
    if (d < 64) {
        float s = 0.f;
        #pragma unroll
        for (int c = 0; c < 8; c++)
            s += part[((size_t)c * (B_ * NH_) + bn) * (M_ * HD_) + (size_t)d * M_ + m];
        kvT[(size_t)bn * (HD_ * M_) + (size_t)d * M_ + m] = __float2bfloat16(s);
    } else {
        float s = 0.f;
        #pragma unroll
        for (int c = 0; c < 8; c++) s += kpart[((size_t)bn * 8 + c) * M_ + m];
        ksum[(size_t)bn * M_ + m] = s;
    }
}

// ---------------- fused per-layer weight prep (+ GMAXU reset)
__global__ __launch_bounds__(256) void prep_kernel(
    const float* __restrict__ wq_l, const float* __restrict__ wk_l,
    const float* __restrict__ wv_l, const float* __restrict__ wo_l,
    const float* __restrict__ wi_l, const float* __restrict__ wo2_l,
    const float* __restrict__ proj_l,
    const float* __restrict__ bq_l, const float* __restrict__ bk_l, const float* __restrict__ bv_l,
    __hip_bfloat16* __restrict__ wqT, __hip_bfloat16* __restrict__ wkT,
    __hip_bfloat16* __restrict__ wvT, __hip_bfloat16* __restrict__ woT,
    __hip_bfloat16* __restrict__ wiT, __hip_bfloat16* __restrict__ wo2T,
    __hip_bfloat16* __restrict__ projb, float* __restrict__ biasq,
    unsigned* __restrict__ gmaxu)
{
    __shared__ float tile[32][33];
    int bid = blockIdx.x;
    if (bid < 6912) {
        const float* src; __hip_bfloat16* dst; int K, N, kt, nt;
        if (bid < 2304) {
            int t = bid / 576, idx = bid % 576;
            src = (t == 0) ? wq_l : (t == 1) ? wk_l : (t == 2) ? wv_l : wo_l;
            dst = (t == 0) ? wqT : (t == 1) ? wkT : (t == 2) ? wvT : woT;
            K = 768; N = 768; kt = idx % 24; nt = idx / 24;
        } else if (bid < 4608) {
            int idx = bid - 2304;
            src = wi_l; dst = wiT; K = 768; N = 3072;
            kt = idx % 24; nt = idx / 24;
        } else {
            int idx = bid - 4608;
            src = wo2_l; dst = wo2T; K = 3072; N = 768;
            kt = idx % 96; nt = idx / 96;
        }
        int k0 = kt * 32, n0 = nt * 32;
        int tx = threadIdx.x & 31, ty = threadIdx.x >> 5;
        #pragma unroll
        for (int i = 0; i < 4; i++)
            tile[ty + i * 8][tx] = src[(size_t)(k0 + ty + i * 8) * N + n0 + tx];
        __syncthreads();
        #pragma unroll
        for (int i = 0; i < 4; i++)
            dst[(size_t)(n0 + ty + i * 8) * K + k0 + tx] = __float2bfloat16(tile[tx][ty + i * 8]);
    } else if (bid < 6976) {
        int i = (bid - 6912) * 256 + threadIdx.x;
        projb[i] = __float2bfloat16(proj_l[i]);
    } else if (bid < 6985) {
        int i = (bid - 6976) * 256 + threadIdx.x;
        if (i < 768) biasq[i] = bq_l[i];
        else if (i < 1536) biasq[i] = bk_l[i - 768];
        else if (i < 2304) biasq[i] = bv_l[i - 1536];
    } else {
        if (threadIdx.x < 24) gmaxu[threadIdx.x] = 0u;
    }
}

// x = LN(word_emb + pos_emb + type_emb); fp32 + bf16 shadow
__global__ __launch_bounds__(256) void embed_ln_kernel(
    const int* __restrict__ ids, const int* __restrict__ tts, const int* __restrict__ pos,
    const float* __restrict__ wemb, const float* __restrict__ pemb, const float* __restrict__ temb,
    const float* __restrict__ g, const float* __restrict__ bb,
    float* __restrict__ out, __hip_bfloat16* __restrict__ outb)
{
    size_t row = blockIdx.x;
    int id = ids[row], tt = tts[row], ps = pos[row];
    const float* w0 = wemb + (size_t)id * H_;
    const float* p0 = pemb + (size_t)ps * H_;
    const float* t0 = temb + (size_t)tt * H_;
    float vals[3], s1 = 0.f, s2 = 0.f;
    #pragma unroll
    for (int i = 0; i < 3; i++) {
        int h = threadIdx.x + i * 256;
        float v = w0[h] + p0[h] + t0[h];
        vals[i] = v; s1 += v; s2 += v * v;
    }
    blockReduceSum2(s1, s2);
    float mu = s1 * (1.0f / H_);
    float var = s2 * (1.0f / H_) - mu * mu;
    float rs = rsqrtf(var + EPS_);
    #pragma unroll
    for (int i = 0; i < 3; i++) {
        int h = threadIdx.x + i * 256;
        float y = (vals[i] - mu) * rs * g[h] + bb[h];
        out[row * H_ + h] = y;
        outb[row * H_ + h] = __float2bfloat16(y);
    }
}

// out = LN(P + Q); fp32 + optional bf16 shadow
__global__ __launch_bounds__(256) void add_ln_kernel(
    const float* __restrict__ P, const float* __restrict__ Q,
    const float* __restrict__ g, const float* __restrict__ bb,
    float* __restrict__ out, __hip_bfloat16* __restrict__ outb)
{
    size_t row = blockIdx.x;
    float vals[3], s1 = 0.f, s2 = 0.f;
    #pragma unroll
    for (int i = 0; i < 3; i++) {
        int h = threadIdx.x + i * 256;
        float v = P[row * H_ + h] + Q[row * H_ + h];
        vals[i] = v; s1 += v; s2 += v * v;
    }
    blockReduceSum2(s1, s2);
    float mu = s1 * (1.0f / H_);
    float var = s2 * (1.0f / H_) - mu * mu;
    float rs = rsqrtf(var + EPS_);
    #pragma unroll
    for (int i = 0; i < 3; i++) {
        int h = threadIdx.x + i * 256;
        float y = (vals[i] - mu) * rs * g[h] + bb[h];
        out[row * H_ + h] = y;
        if (outb) outb[row * H_ + h] = __float2bfloat16(y);
    }
}

// out = LN(p0 + p1 + bias + Q); fp32 + bf16 shadow (FFN2 split-K reduce + LN2)
__global__ __launch_bounds__(256) void add_ln3_kernel(
    const float* __restrict__ planes, const float* __restrict__ bias,
    const float* __restrict__ Q,
    const float* __restrict__ g, const float* __restrict__ bb,
    float* __restrict__ out, __hip_bfloat16* __restrict__ outb)
{
    size_t row = blockIdx.x;
    float vals[3], s1 = 0.f, s2 = 0.f;
    #pragma unroll
    for (int i = 0; i < 3; i++) {
        int h = threadIdx.x + i * 256;
        size_t e = row * H_ + h;
        float v = planes[e] + planes[NXH_ + e] + bias[h] + Q[e];
        vals[i] = v; s1 += v; s2 += v * v;
    }
    blockReduceSum2(s1, s2);
    float mu = s1 * (1.0f / H_);
    float var = s2 * (1.0f / H_) - mu * mu;
    float rs = rsqrtf(var + EPS_);
    #pragma unroll
    for (int i = 0; i < 3; i++) {
        int h = threadIdx.x + i * 256;
        float y = (vals[i] - mu) * rs * g[h] + bb[h];
        out[row * H_ + h] = y;
        outb[row * H_ + h] = __float2bfloat16(y);
    }
}

extern "C" void kernel_launch(void* const* d_in, const int* in_sizes, int n_in,
                              void* d_out, int out_size, void* d_ws, size_t ws_size,
                              hipStream_t stream)
{
    const int* input_ids  = (const int*)d_in[0];
    const int* token_type = (const int*)d_in[1];
    const int* position   = (const int*)d_in[2];
    const int* amask      = (const int*)d_in[3];
    const float* wemb = (const float*)d_in[4];
    const float* pemb = (const float*)d_in[5];
    const float* temb = (const float*)d_in[6];
    const float* elng = (const float*)d_in[7];
    const float* elnb = (const float*)d_in[8];
    const float* wq  = (const float*)d_in[9];
    const float* bq  = (const float*)d_in[10];
    const float* wk  = (const float*)d_in[11];
    const float* bk  = (const float*)d_in[12];
    const float* wv  = (const float*)d_in[13];
    const float* bv  = (const float*)d_in[14];
    const float* wo  = (const float*)d_in[15];
    const float* bo  = (const float*)d_in[16];
    const float* ln1g = (const float*)d_in[17];
    const float* ln1b = (const float*)d_in[18];
    const float* wi  = (const float*)d_in[19];
    const float* bi  = (const float*)d_in[20];
    const float* wo2 = (const float*)d_in[21];
    const float* bo2 = (const float*)d_in[22];
    const float* ln2g = (const float*)d_in[23];
    const float* ln2b = (const float*)d_in[24];
    const float* proj = (const float*)d_in[25];

    float* ws = (float*)d_ws;
    float* X    = ws;                          // 3145728
    float* T2   = X + 3145728;                 // 3145728
    float* BIG  = T2 + 3145728;                // 12582912 (kfeat bf16 / FFN1 out bf16)
    float* U    = BIG + 12582912;              // 6291456 (PART / FFN2 planes)
    __hip_bfloat16* Xb  = (__hip_bfloat16*)(U + 6291456);            // 3145728 el
    __hip_bfloat16* Qb  = (__hip_bfloat16*)((float*)Xb + 1572864);   // Qb|Kb|Vb contiguous
    __hip_bfloat16* Kb  = Qb + 3145728;
    __hip_bfloat16* Vb  = Kb + 3145728;
    __hip_bfloat16* BF1 = Vb + 3145728;                              // 3145728 el
    __hip_bfloat16* WT  = BF1 + 3145728;                             // 7094272 el
    float* kvT_f = (float*)(WT + 7094272);     // kvT bf16 393216 el = 196608 f
    __hip_bfloat16* kvT = (__hip_bfloat16*)kvT_f;
    float* KSUM  = kvT_f + 196608;             // 6144
    float* KPART = KSUM + 6144;                // 49152 used (24*8*256)
    float* RSVD  = KPART + 196608;             // unused
    unsigned* GMAXU = (unsigned*)(RSVD + 98304); // 24 used
    float* QD    = (float*)GMAXU + 64;         // 49152  (KD follows contiguously)
    float* KD    = QD + 49152;                 // 49152
    float* BIASQ = KD + 49152;                 // 2304
    float* T1    = (float*)d_out;              // [4096,768] scratch aliasing output

    __hip_bfloat16* wqT  = WT;                 // packed QKV^T contiguous [2304,768]
    __hip_bfloat16* wkT  = wqT + 589824;
    __hip_bfloat16* wvT  = wkT + 589824;
    __hip_bfloat16* woT  = wvT + 589824;
    __hip_bfloat16* wiT  = woT + 589824;
    __hip_bfloat16* wo2T = wiT + 2359296;
    __hip_bfloat16* projb = wo2T + 2359296;    // 16384 el
    float* PART = U;                           // kv partials (dead after kvred)
    float* PLANES = U;                         // FFN2 split-K planes (2 x NXH_)
    __hip_bfloat16* BIGb = (__hip_bfloat16*)BIG;   // kfeat [49152][256] bf16 / FFN1 out

    embed_ln_kernel<<<BS_, 256, 0, stream>>>(input_ids, token_type, position,
        wemb, pemb, temb, elng, elnb, X, Xb);

    for (int l = 0; l < L_; l++) {
        const float* wq_l = wq + (size_t)l * H_ * NH_ * HD_;
        const float* wk_l = wk + (size_t)l * H_ * NH_ * HD_;
        const float* wv_l = wv + (size_t)l * H_ * NH_ * HD_;
        const float* wo_l = wo + (size_t)l * NH_ * HD_ * H_;
        const float* bq_l = bq + (size_t)l * NH_ * HD_;
        const float* bk_l = bk + (size_t)l * NH_ * HD_;
        const float* bv_l = bv + (size_t)l * NH_ * HD_;
        const float* bo_l = bo + (size_t)l * H_;
        const float* wi_l = wi + (size_t)l * H_ * I_;
        const float* bi_l = bi + (size_t)l * I_;
        const float* wo2_l = wo2 + (size_t)l * I_ * H_;
        const float* bo2_l = bo2 + (size_t)l * H_;
        const float* proj_l = proj + (size_t)l * M_ * HD_;

        // ---- fused weight prep + GMAXU reset ----
        prep_kernel<<<6986, 256, 0, stream>>>(wq_l, wk_l, wv_l, wo_l, wi_l, wo2_l, proj_l,
            bq_l, bk_l, bv_l, wqT, wkT, wvT, woT, wiT, wo2T, projb, BIASQ, GMAXU);

        // ---- fused QKV GEMM -> Qb|Kb|Vb bf16 + qd/kd (wide 256x128 pipe3) ----
        gemm_pipe3w_kernel<0,2><<<dim3(18,16), 256, 0, stream>>>(
            Xb, wqT, BIASQ, (void*)Qb, 768, 768, 768, 768, QD);

        // ---- K path: proj-K (bf16 features + atomic gmax) -> fused k'/kv/ksum ----
        gemm_projk_kernel<<<dim3(2,384), 256, 0, stream>>>(
            Kb, projb, BIGb, 64, 64, 64, 256, DN_, GMAXU);
        kv_fused_kernel<<<dim3(4, B_*NH_, 8), 256, 0, stream>>>(
            BIGb, Vb, KD, GMAXU, amask, PART, KPART);
        kvred_kernel<<<dim3(B_*NH_, HD_+1), 256, 0, stream>>>(PART, kvT, KPART, KSUM);

        // ---- Q path: fully fused proj + rowmax + q' + den + num ----
        qnum_fused_kernel<<<dim3(16, B_*NH_), 512, 0, stream>>>(
            Qb, projb, QD, KSUM, kvT, BF1);

        // ---- attn out proj + LN1 ----
        gemm_pipe3_n64_kernel<<<dim3(12,32), 256, 0, stream>>>(
            BF1, woT, bo_l, T1, 768, 768, 768, 768);
        add_ln_kernel<<<BS_, 256, 0, stream>>>(T1, X, ln1g + (size_t)l*H_, ln1b + (size_t)l*H_, T2, BF1);

        // ---- FFN1 (gelu, bf16 out, wide pipe3) ----
        gemm_pipe3w_kernel<1,1><<<dim3(24,16), 256, 0, stream>>>(
            BF1, wiT, bi_l, (void*)BIGb, 768, 768, 768, 3072, nullptr);

        // ---- FFN2: split-K x2 wide pipe3 -> fp32 planes + fused reduce/LN2 ----
        gemm_pipe3w_kernel<0,3><<<dim3(6,16,2), 256, 0, stream>>>(
            BIGb, wo2T, nullptr, nullptr, 1536, 3072, 3072, 768, PLANES);
        float* xout = (l == L_ - 1) ? (float*)d_out : X;
        add_ln3_kernel<<<BS_, 256, 0, stream>>>(PLANES, bo2_l, T2,
            ln2g + (size_t)l*H_, ln2b + (size_t)l*H_, xout, Xb);
    }
}

// Round 13
// 1618.213 us; speedup vs baseline: 1.4295x; 1.4295x over previous
//
#include <hip/hip_runtime.h>
#include <hip/hip_bf16.h>

#define B_ 2
#define S_ 2048
#define H_ 768
#define NH_ 12
#define HD_ 64
#define L_ 6
#define I_ 3072
#define M_ 256
#define BS_ 4096           // B*S
#define R_ 49152           // B*S*NH
#define NXH_ 3145728       // BS*H
#define EPS_ 1e-6f
#define DN_ 0.35355339059327373f   // 1/sqrt(sqrt(64))
#define RATIO_ 0.0625f             // 1/sqrt(256)

typedef __attribute__((ext_vector_type(8))) short bf16x8;
typedef __attribute__((ext_vector_type(4))) float f32x4;

__device__ __forceinline__ void gload16(const void* g, void* l) {
    __builtin_amdgcn_global_load_lds(
        (const __attribute__((address_space(1))) void*)g,
        (__attribute__((address_space(3))) void*)l, 16, 0, 0);
}

__device__ __forceinline__ float gelu_f(float x) {
    const float c = 0.7978845608028654f;
    float x3 = x * x * x;
    return 0.5f * x * (1.0f + tanhf(c * (x + 0.044715f * x3)));
}

// monotone float<->uint encoding for atomicMax on floats (exact, order-independent)
__device__ __forceinline__ unsigned enc_f(float f) {
    unsigned u = __float_as_uint(f);
    return (u & 0x80000000u) ? ~u : (u | 0x80000000u);
}
__device__ __forceinline__ float dec_f(unsigned u) {
    return (u & 0x80000000u) ? __uint_as_float(u & 0x7fffffffu) : __uint_as_float(~u);
}

__device__ __forceinline__ void blockReduceSum2(float& a, float& b) {
    __shared__ float sa[4], sb[4];
    int lane = threadIdx.x & 63, wid = threadIdx.x >> 6;
    #pragma unroll
    for (int off = 32; off; off >>= 1) {
        a += __shfl_down(a, off, 64);
        b += __shfl_down(b, off, 64);
    }
    __syncthreads();
    if (lane == 0) { sa[wid] = a; sb[wid] = b; }
    __syncthreads();
    a = sa[0] + sa[1] + sa[2] + sa[3];
    b = sb[0] + sb[1] + sb[2] + sb[3];
    __syncthreads();
}

// ============== gemm_pipe3: 128x128 tile, 4 waves, BK=32, depth-3 LDS ring (48 KB),
// counted vmcnt, two raw barriers/iter, setprio, chunk-XOR swizzle.
// OUTMODE: 1 = bf16 out (+ACT gelu), 2 = QKV split bf16 + fused qd/kd,
//          3 = split-K fp32 plane (aux + blockIdx.z*NXH_), no bias/act
template<int ACT, int OUTMODE>
__global__ __launch_bounds__(256) void gemm_pipe3_kernel(
    const __hip_bfloat16* __restrict__ A, const __hip_bfloat16* __restrict__ BT,
    const float* __restrict__ bias, void* __restrict__ Cv,
    int K, int lda, int ldb, int ldc, float* __restrict__ aux)
{
    __shared__ __align__(16) unsigned short As[3][128][32];   // 24 KB
    __shared__ __align__(16) unsigned short Bs[3][128][32];   // 24 KB
    const int tid = threadIdx.x, lane = tid & 63, wid = tid >> 6;
    const int wr = wid >> 1, wc = wid & 1;
    const size_t r0 = (size_t)blockIdx.y * 128;
    const int n0 = blockIdx.x * 128;
    const size_t kbase = (size_t)blockIdx.z * (size_t)K;

    const int srow = lane >> 2;
    const int selem = ((lane & 3) ^ ((srow >> 1) & 3)) * 8;   // pre-swizzled source chunk
    const unsigned short* ga0 = (const unsigned short*)A + (r0 + wid * 32 + srow) * (size_t)lda + kbase + selem;
    const unsigned short* gb0 = (const unsigned short*)BT + ((size_t)n0 + wid * 32 + srow) * (size_t)ldb + kbase + selem;

    f32x4 acc[4][4];
    #pragma unroll
    for (int i = 0; i < 4; i++)
        #pragma unroll
        for (int j = 0; j < 4; j++)
            acc[i][j] = (f32x4){0.f, 0.f, 0.f, 0.f};

    const int lr = lane & 15;
    const int rc8 = (((lane >> 4) ^ ((lr >> 1) & 3))) * 8;    // swizzled read chunk

#define STAGE_(t) { const int bb_ = (t) % 3; const int kk_ = (t) * 32;            \
    gload16(ga0 + kk_, &As[bb_][wid * 32][0]);                                    \
    gload16(ga0 + kk_ + 16 * (size_t)lda, &As[bb_][wid * 32 + 16][0]);            \
    gload16(gb0 + kk_, &Bs[bb_][wid * 32][0]);                                    \
    gload16(gb0 + kk_ + 16 * (size_t)ldb, &Bs[bb_][wid * 32 + 16][0]); }

#define ITER_(t, VMSTR, DOSTAGE) {                                                \
    if (DOSTAGE) STAGE_((t) + 2);                                                 \
    asm volatile("s_waitcnt vmcnt(" VMSTR ")" ::: "memory");                      \
    __builtin_amdgcn_sched_barrier(0);                                            \
    __builtin_amdgcn_s_barrier();                                                 \
    __builtin_amdgcn_sched_barrier(0);                                            \
    const int bb_ = (t) % 3;                                                      \
    bf16x8 af[4], bfv[4];                                                         \
    _Pragma("unroll") for (int i = 0; i < 4; i++)                                 \
        af[i] = *(const bf16x8*)&As[bb_][wr * 64 + i * 16 + lr][rc8];             \
    _Pragma("unroll") for (int j = 0; j < 4; j++)                                 \
        bfv[j] = *(const bf16x8*)&Bs[bb_][wc * 64 + j * 16 + lr][rc8];            \
    __builtin_amdgcn_s_setprio(1);                                                \
    _Pragma("unroll") for (int i = 0; i < 4; i++)                                 \
        _Pragma("unroll") for (int j = 0; j < 4; j++)                             \
            acc[i][j] = __builtin_amdgcn_mfma_f32_16x16x32_bf16(af[i], bfv[j], acc[i][j], 0, 0, 0); \
    __builtin_amdgcn_s_setprio(0);                                                \
    __builtin_amdgcn_s_barrier();                                                 \
    __builtin_amdgcn_sched_barrier(0); }

    const int nT = K >> 5;
    STAGE_(0); STAGE_(1);
    for (int t = 0; t < nT - 2; ++t) ITER_(t, "8", true);
    ITER_(nT - 2, "4", false);
    ITER_(nT - 1, "0", false);
#undef ITER_
#undef STAGE_

    const int rr = (lane >> 4) * 4;
    const int cc = lane & 15;
    if (OUTMODE == 3) {
        float* fpl = aux + (size_t)blockIdx.z * NXH_;
        #pragma unroll
        for (int i = 0; i < 4; i++) {
            #pragma unroll
            for (int j = 0; j < 4; j++) {
                size_t col = (size_t)n0 + wc * 64 + j * 16 + cc;
                #pragma unroll
                for (int rg = 0; rg < 4; rg++) {
                    size_t row = r0 + wr * 64 + i * 16 + rr + rg;
                    fpl[row * (size_t)ldc + col] = acc[i][j][rg];
                }
            }
        }
    } else if (OUTMODE == 1) {
        #pragma unroll
        for (int i = 0; i < 4; i++) {
            #pragma unroll
            for (int j = 0; j < 4; j++) {
                size_t col = (size_t)n0 + wc * 64 + j * 16 + cc;
                float bv_ = bias ? bias[col] : 0.f;
                #pragma unroll
                for (int rg = 0; rg < 4; rg++) {
                    size_t row = r0 + wr * 64 + i * 16 + rr + rg;
                    float v = acc[i][j][rg] + bv_;
                    if (ACT == 1) v = gelu_f(v);
                    ((__hip_bfloat16*)Cv)[row * (size_t)ldc + col] = __float2bfloat16(v);
                }
            }
        }
    } else {  // OUTMODE 2: QKV split + fused qd/kd
        const size_t seg = (size_t)n0 / 768;
        const int colbase = n0 - (int)seg * 768;
        #pragma unroll
        for (int i = 0; i < 4; i++) {
            #pragma unroll
            for (int rg = 0; rg < 4; rg++) {
                size_t row = r0 + wr * 64 + i * 16 + rr + rg;
                float ss = 0.f;
                #pragma unroll
                for (int j = 0; j < 4; j++) {
                    int colw = wc * 64 + j * 16 + cc;
                    size_t col = (size_t)n0 + colw;
                    float bv_ = bias ? bias[col] : 0.f;
                    float v = acc[i][j][rg] + bv_;
                    __hip_bfloat16 hb = __float2bfloat16(v);
                    ((__hip_bfloat16*)Cv)[seg * (size_t)NXH_ + row * 768 + colbase + colw] = hb;
                    float vr = __bfloat162float(hb);
                    ss += vr * vr;
                }
                #pragma unroll
                for (int off = 1; off <= 8; off <<= 1)
                    ss += __shfl_xor(ss, off, 64);
                if (seg < 2 && (lane & 15) == 0) {
                    int nh = colbase / 64 + wc;
                    aux[seg * (size_t)R_ + row * 12 + nh] = 0.5f * DN_ * DN_ * ss;
                }
            }
        }
    }
}

// ============== gemm_pipe3_n64: 128x64 tile, depth-3 ring (36 KB), fp32 out + bias.
__global__ __launch_bounds__(256) void gemm_pipe3_n64_kernel(
    const __hip_bfloat16* __restrict__ A, const __hip_bfloat16* __restrict__ BT,
    const float* __restrict__ bias, float* __restrict__ C,
    int K, int lda, int ldb, int ldc)
{
    __shared__ __align__(16) unsigned short As[3][128][32];   // 24 KB
    __shared__ __align__(16) unsigned short Bs[3][64][32];    // 12 KB
    const int tid = threadIdx.x, lane = tid & 63, wid = tid >> 6;
    const size_t r0 = (size_t)blockIdx.y * 128;
    const int n0 = blockIdx.x * 64;

    const int srow = lane >> 2;
    const int selem = ((lane & 3) ^ ((srow >> 1) & 3)) * 8;
    const unsigned short* ga0 = (const unsigned short*)A + (r0 + wid * 32 + srow) * (size_t)lda + selem;
    const unsigned short* gb0 = (const unsigned short*)BT + ((size_t)n0 + wid * 16 + srow) * (size_t)ldb + selem;

    f32x4 acc[2][4];
    #pragma unroll
    for (int i = 0; i < 2; i++)
        #pragma unroll
        for (int j = 0; j < 4; j++)
            acc[i][j] = (f32x4){0.f, 0.f, 0.f, 0.f};

    const int lr = lane & 15;
    const int rc8 = (((lane >> 4) ^ ((lr >> 1) & 3))) * 8;

#define STAGE_(t) { const int bb_ = (t) % 3; const int kk_ = (t) * 32;            \
    gload16(ga0 + kk_, &As[bb_][wid * 32][0]);                                    \
    gload16(ga0 + kk_ + 16 * (size_t)lda, &As[bb_][wid * 32 + 16][0]);            \
    gload16(gb0 + kk_, &Bs[bb_][wid * 16][0]); }

#define ITER_(t, VMSTR, DOSTAGE) {                                                \
    if (DOSTAGE) STAGE_((t) + 2);                                                 \
    asm volatile("s_waitcnt vmcnt(" VMSTR ")" ::: "memory");                      \
    __builtin_amdgcn_sched_barrier(0);                                            \
    __builtin_amdgcn_s_barrier();                                                 \
    __builtin_amdgcn_sched_barrier(0);                                            \
    const int bb_ = (t) % 3;                                                      \
    bf16x8 af[2], bfv[4];                                                         \
    _Pragma("unroll") for (int i = 0; i < 2; i++)                                 \
        af[i] = *(const bf16x8*)&As[bb_][wid * 32 + i * 16 + lr][rc8];            \
    _Pragma("unroll") for (int j = 0; j < 4; j++)                                 \
        bfv[j] = *(const bf16x8*)&Bs[bb_][j * 16 + lr][rc8];                      \
    __builtin_amdgcn_s_setprio(1);                                                \
    _Pragma("unroll") for (int i = 0; i < 2; i++)                                 \
        _Pragma("unroll") for (int j = 0; j < 4; j++)                             \
            acc[i][j] = __builtin_amdgcn_mfma_f32_16x16x32_bf16(af[i], bfv[j], acc[i][j], 0, 0, 0); \
    __builtin_amdgcn_s_setprio(0);                                                \
    __builtin_amdgcn_s_barrier();                                                 \
    __builtin_amdgcn_sched_barrier(0); }

    const int nT = K >> 5;
    STAGE_(0); STAGE_(1);
    for (int t = 0; t < nT - 2; ++t) ITER_(t, "6", true);
    ITER_(nT - 2, "3", false);
    ITER_(nT - 1, "0", false);
#undef ITER_
#undef STAGE_

    const int rr = (lane >> 4) * 4, cc = lane & 15;
    #pragma unroll
    for (int i = 0; i < 2; i++) {
        #pragma unroll
        for (int j = 0; j < 4; j++) {
            int col = n0 + j * 16 + cc;
            float bv_ = bias ? bias[col] : 0.f;
            #pragma unroll
            for (int rg = 0; rg < 4; rg++) {
                size_t row = r0 + wid * 32 + i * 16 + rr + rg;
                C[row * (size_t)ldc + col] = acc[i][j][rg] + bv_;
            }
        }
    }
}

// ---------------- proj-K: 128x128 tile, 2-phase dbuf, bf16 C out + atomic global max
__global__ __launch_bounds__(256) void gemm_projk_kernel(
    const __hip_bfloat16* __restrict__ A, const __hip_bfloat16* __restrict__ BT,
    __hip_bfloat16* __restrict__ Cv,
    int K, int lda, int ldb, int ldc, float alpha,
    unsigned* __restrict__ gmaxu)
{
    __shared__ __align__(16) unsigned short As[2][128][32];
    __shared__ __align__(16) unsigned short Bs[2][128][32];
    __shared__ float rmx[128][2];
    __shared__ float rowm[128];
    const int tid = threadIdx.x, lane = tid & 63, wid = tid >> 6;
    const int wr = wid >> 1, wc = wid & 1;
    const size_t r0 = (size_t)blockIdx.y * 128;
    const int n0 = blockIdx.x * 128;

    const int srow = lane >> 2;
    const int selem = ((lane & 3) ^ ((srow >> 1) & 3)) * 8;
    const unsigned short* ga0 = (const unsigned short*)A + (r0 + wid * 32 + srow) * (size_t)lda + selem;
    const unsigned short* gb0 = (const unsigned short*)BT + ((size_t)n0 + wid * 32 + srow) * (size_t)ldb + selem;

    f32x4 acc[4][4];
    #pragma unroll
    for (int i = 0; i < 4; i++)
        #pragma unroll
        for (int j = 0; j < 4; j++)
            acc[i][j] = (f32x4){0.f, 0.f, 0.f, 0.f};

    gload16(ga0, &As[0][wid * 32][0]);
    gload16(ga0 + 16 * (size_t)lda, &As[0][wid * 32 + 16][0]);
    gload16(gb0, &Bs[0][wid * 32][0]);
    gload16(gb0 + 16 * (size_t)ldb, &Bs[0][wid * 32 + 16][0]);
    __syncthreads();

    const int lr = lane & 15;
    const int rc8 = (((lane >> 4) ^ ((lr >> 1) & 3))) * 8;

    int cur = 0;
    for (int k0 = 0; k0 < K; k0 += 32) {
        const int kn = k0 + 32;
        if (kn < K) {
            gload16(ga0 + kn, &As[cur ^ 1][wid * 32][0]);
            gload16(ga0 + kn + 16 * (size_t)lda, &As[cur ^ 1][wid * 32 + 16][0]);
            gload16(gb0 + kn, &Bs[cur ^ 1][wid * 32][0]);
            gload16(gb0 + kn + 16 * (size_t)ldb, &Bs[cur ^ 1][wid * 32 + 16][0]);
        }
        bf16x8 af[4], bfv[4];
        #pragma unroll
        for (int i = 0; i < 4; i++)
            af[i] = *(const bf16x8*)&As[cur][wr * 64 + i * 16 + lr][rc8];
        #pragma unroll
        for (int j = 0; j < 4; j++)
            bfv[j] = *(const bf16x8*)&Bs[cur][wc * 64 + j * 16 + lr][rc8];
        #pragma unroll
        for (int i = 0; i < 4; i++)
            #pragma unroll
            for (int j = 0; j < 4; j++)
                acc[i][j] = __builtin_amdgcn_mfma_f32_16x16x32_bf16(af[i], bfv[j], acc[i][j], 0, 0, 0);
        __syncthreads();
        cur ^= 1;
    }

    const int rr = (lane >> 4) * 4;
    const int cc = lane & 15;
    #pragma unroll
    for (int i = 0; i < 4; i++) {
        #pragma unroll
        for (int j = 0; j < 4; j++) {
            int colw = wc * 64 + j * 16 + cc;
            size_t col = (size_t)n0 + colw;
            #pragma unroll
            for (int rg = 0; rg < 4; rg++) {
                size_t row = r0 + wr * 64 + i * 16 + rr + rg;
                Cv[row * ldc + col] = __float2bfloat16(acc[i][j][rg] * alpha);
            }
        }
    }
    #pragma unroll
    for (int i = 0; i < 4; i++) {
        #pragma unroll
        for (int rg = 0; rg < 4; rg++) {
            float rm = -3.4e38f;
            #pragma unroll
            for (int j = 0; j < 4; j++) rm = fmaxf(rm, acc[i][j][rg] * alpha);
            #pragma unroll
            for (int off = 1; off <= 8; off <<= 1)
                rm = fmaxf(rm, __shfl_xor(rm, off, 64));
            if ((lane & 15) == 0) rmx[wr * 64 + i * 16 + rr + rg][wc] = rm;
        }
    }
    __syncthreads();
    if (tid < 128) rowm[tid] = fmaxf(rmx[tid][0], rmx[tid][1]);
    __syncthreads();
    if (tid < 12) {
        int b = (int)(r0 / 24576);
        int h = (int)((r0 + tid) % 12);
        float m = -3.4e38f;
        for (int k = tid; k < 128; k += 12) m = fmaxf(m, rowm[k]);
        atomicMax(&gmaxu[b * 12 + h], enc_f(m));
    }
}

// ---------------- FUSED proj-Q + rowmax + q' + den + num. Grid (16, 24) x 512 thr.
__global__ __launch_bounds__(512) void qnum_fused_kernel(
    const __hip_bfloat16* __restrict__ Qbp, const __hip_bfloat16* __restrict__ projb,
    const float* __restrict__ qd, const float* __restrict__ ksum,
    const __hip_bfloat16* __restrict__ kvT, __hip_bfloat16* __restrict__ ATT)
{
    __shared__ __align__(16) unsigned short Pl[128][256];     // 64 KB (q'; overlays Asm/Bsm)
    __shared__ __align__(16) unsigned short kvTl[64][256];    // 32 KB
    __shared__ float ksl[256];
    __shared__ float qdl[128];
    __shared__ float red[128][4];
    __shared__ float rmaxv[128];
    __shared__ float deni[128];
    unsigned short (*Asm)[64] = (unsigned short (*)[64])&Pl[0][0];            // [128][64]
    unsigned short (*Bsm)[64] = (unsigned short (*)[64])(&Pl[0][0] + 8192);   // [256][64]

    const int tid = threadIdx.x, lane = tid & 63, w = tid >> 6;
    const int wrow = w >> 2, wcol = w & 3;
    const int bn = blockIdx.y, b = bn / NH_, n = bn % NH_;
    const size_t r0g = (size_t)b * S_ + (size_t)blockIdx.x * 128;

    if (tid < 256) ksl[tid] = ksum[(size_t)bn * 256 + tid];
    else if (tid < 384) qdl[tid - 256] = qd[(r0g + tid - 256) * 12 + n];

    const int lrow = lane >> 3, lch = lane & 7;
    const int sch = (lch ^ (lrow & 7)) * 8;
    gload16((const unsigned short*)Qbp + (r0g + w * 16 + lrow) * 768 + n * 64 + sch, &Asm[w * 16][0]);
    gload16((const unsigned short*)Qbp + (r0g + w * 16 + 8 + lrow) * 768 + n * 64 + sch, &Asm[w * 16 + 8][0]);
    #pragma unroll
    for (int p = 0; p < 4; p++)
        gload16((const unsigned short*)projb + (size_t)(w * 32 + p * 8 + lrow) * 64 + sch,
                &Bsm[w * 32 + p * 8][0]);
    {
        const int rIn = lane >> 5, c32 = lane & 31;
        #pragma unroll
        for (int p = 0; p < 4; p++) {
            int d = w * 8 + p * 2 + rIn;
            gload16((const unsigned short*)kvT + (size_t)bn * (HD_ * M_) + (size_t)d * 256
                    + (c32 ^ (d & 7)) * 8, &kvTl[w * 8 + p * 2][0]);
        }
    }
    __syncthreads();

    const int lr = lane & 15, kq = lane >> 4;
    f32x4 acc[4][4];
    #pragma unroll
    for (int i = 0; i < 4; i++)
        #pragma unroll
        for (int j = 0; j < 4; j++)
            acc[i][j] = (f32x4){0.f, 0.f, 0.f, 0.f};

    // phase 1: qp = Q . proj^T  (K=64, 2 k-steps)
    #pragma unroll
    for (int ks = 0; ks < 2; ks++) {
        const int ch = (((ks << 2) | kq) ^ (lr & 7)) * 8;
        bf16x8 af[4], bfv[4];
        #pragma unroll
        for (int i = 0; i < 4; i++)
            af[i] = *(const bf16x8*)&Asm[wrow * 64 + i * 16 + lr][ch];
        #pragma unroll
        for (int j = 0; j < 4; j++)
            bfv[j] = *(const bf16x8*)&Bsm[wcol * 64 + j * 16 + lr][ch];
        #pragma unroll
        for (int i = 0; i < 4; i++)
            #pragma unroll
            for (int j = 0; j < 4; j++)
                acc[i][j] = __builtin_amdgcn_mfma_f32_16x16x32_bf16(af[i], bfv[j], acc[i][j], 0, 0, 0);
    }

    // phase 2: row-max over 256 cols
    #pragma unroll
    for (int i = 0; i < 4; i++) {
        #pragma unroll
        for (int rg = 0; rg < 4; rg++) {
            float rm = -3.4e38f;
            #pragma unroll
            for (int j = 0; j < 4; j++) rm = fmaxf(rm, acc[i][j][rg] * DN_);
            #pragma unroll
            for (int off = 1; off <= 8; off <<= 1)
                rm = fmaxf(rm, __shfl_xor(rm, off, 64));
            if ((lane & 15) == 0) red[wrow * 64 + i * 16 + kq * 4 + rg][wcol] = rm;
        }
    }
    __syncthreads();
    if (tid < 128)
        rmaxv[tid] = fmaxf(fmaxf(red[tid][0], red[tid][1]), fmaxf(red[tid][2], red[tid][3]));
    __syncthreads();

    // phase 3: q' -> bf16 in LDS (swizzled) + den partials
    #pragma unroll
    for (int i = 0; i < 4; i++) {
        #pragma unroll
        for (int rg = 0; rg < 4; rg++) {
            int row = wrow * 64 + i * 16 + kq * 4 + rg;
            float qdv = qdl[row], mx = rmaxv[row];
            float dsum = 0.f;
            #pragma unroll
            for (int j = 0; j < 4; j++) {
                int col = wcol * 64 + j * 16 + lr;
                float qp = acc[i][j][rg] * DN_;
                float qv = RATIO_ * (expf(qp - qdv - mx) + EPS_);
                __hip_bfloat16 qb = __float2bfloat16(qv);
                Pl[row][((col >> 3) ^ (row & 7)) * 8 + (col & 7)] = *(unsigned short*)&qb;
                dsum += __bfloat162float(qb) * ksl[col];
            }
            #pragma unroll
            for (int off = 1; off <= 8; off <<= 1)
                dsum += __shfl_xor(dsum, off, 64);
            if ((lane & 15) == 0) red[row][wcol] = dsum;
        }
    }
    __syncthreads();
    if (tid < 128)
        deni[tid] = red[tid][0] + red[tid][1] + red[tid][2] + red[tid][3];
    __syncthreads();

    // phase 4: num = q' . kvT^T (K=256, 8 k-steps); wave w owns rows w*16..w*16+15
    f32x4 acc2[4];
    #pragma unroll
    for (int j = 0; j < 4; j++) acc2[j] = (f32x4){0.f, 0.f, 0.f, 0.f};
    #pragma unroll
    for (int ks = 0; ks < 8; ks++) {
        const int mc = ks * 4 + kq;
        const int sl = (mc ^ (lr & 7)) * 8;
        bf16x8 af = *(const bf16x8*)&Pl[w * 16 + lr][sl];
        #pragma unroll
        for (int j = 0; j < 4; j++) {
            bf16x8 bfv = *(const bf16x8*)&kvTl[j * 16 + lr][sl];
            acc2[j] = __builtin_amdgcn_mfma_f32_16x16x32_bf16(af, bfv, acc2[j], 0, 0, 0);
        }
    }
    #pragma unroll
    for (int rg = 0; rg < 4; rg++) {
        int row = w * 16 + kq * 4 + rg;
        float inv = 1.0f / deni[row];
        #pragma unroll
        for (int j = 0; j < 4; j++)
            ATT[(r0g + row) * 768 + n * 64 + j * 16 + lr]
                = __float2bfloat16(acc2[j][rg] * inv);
    }
}

// ---------------- FUSED k' + kv split-K + ksum partials. Grid (4 m0, 24 bn, 8 chunk).
__global__ __launch_bounds__(256) void kv_fused_kernel(
    const __hip_bfloat16* __restrict__ KF, const __hip_bfloat16* __restrict__ Vb,
    const float* __restrict__ kd, const unsigned* __restrict__ gmaxu,
    const int* __restrict__ amask,
    float* __restrict__ part, float* __restrict__ kpart)
{
    const int m0 = blockIdx.x * 64, bn = blockIdx.y, b = bn / NH_, n = bn % NH_;
    const int s0 = blockIdx.z * 256;
    __shared__ __align__(16) float As2[16][68];
    __shared__ __align__(16) float Bs2[16][68];
    __shared__ float sred[4][64];
    const int tid = threadIdx.x, tx = tid & 15, ty = tid >> 4;
    const float gm = dec_f(gmaxu[bn]);
    float acc[4][4] = {};
    float ks = 0.f;
    for (int ss = 0; ss < 256; ss += 16) {
        #pragma unroll
        for (int i = 0; i < 4; i++) {
            int idx = tid + i * 256;
            int kk = idx >> 6, c = idx & 63;
            size_t srow = (size_t)b * S_ + s0 + ss + kk;
            float kdv = kd[srow * 12 + n];
            float mk = (float)amask[srow];
            float kf = __bfloat162float(KF[srow * (NH_ * M_) + n * M_ + m0 + c]);
            float kp = RATIO_ * (expf(kf - kdv - gm) + EPS_) * mk;
            As2[kk][c] = kp;
            ks += kp;
            Bs2[kk][c] = __bfloat162float(Vb[srow * H_ + n * HD_ + c]);
        }
        __syncthreads();
        #pragma unroll
        for (int kk = 0; kk < 16; kk++) {
            float4 av = *reinterpret_cast<const float4*>(&As2[kk][ty * 4]);
            float4 bv = *reinterpret_cast<const float4*>(&Bs2[kk][tx * 4]);
            float a4[4] = {av.x, av.y, av.z, av.w};
            float b4[4] = {bv.x, bv.y, bv.z, bv.w};
            #pragma unroll
            for (int i = 0; i < 4; i++)
                #pragma unroll
                for (int j = 0; j < 4; j++)
                    acc[i][j] += a4[i] * b4[j];
        }
        __syncthreads();
    }
    float* Cb = part + ((size_t)blockIdx.z * (B_ * NH_) + bn) * (M_ * HD_);
    #pragma unroll
    for (int j = 0; j < 4; j++)
        #pragma unroll
        for (int i = 0; i < 4; i++)
            Cb[(size_t)(tx * 4 + j) * M_ + m0 + ty * 4 + i] = acc[i][j];
    sred[tid >> 6][tid & 63] = ks;
    __syncthreads();
    if (tid < 64)
        kpart[((size_t)bn * 8 + blockIdx.z) * M_ + m0 + tid]
            = sred[0][tid] + sred[1][tid] + sred[2][tid] + sred[3][tid];
}

// reduce 8 chunks -> kvT bf16 [bn][d][m] (d<64) OR ksum (blockIdx.y==64). Grid (24, 65).
__global__ __launch_bounds__(256) void kvred_kernel(
    const float* __restrict__ part, __hip_bfloat16* __restrict__ kvT,
    const float* __restrict__ kpart, float* __restrict__ ksum)
{
    const int bn = blockIdx.x, d = blockIdx.y, m = threadIdx.x;
    if (d < 64) {
        float s = 0.f;
        #pragma unroll
        for (int c = 0; c < 8; c++)
            s += part[((size_t)c * (B_ * NH_) + bn) * (M_ * HD_) + (size_t)d * M_ + m];
        kvT[(size_t)bn * (HD_ * M_) + (size_t)d * M_ + m] = __float2bfloat16(s);
    } else {
        float s = 0.f;
        #pragma unroll
        for (int c = 0; c < 8; c++) s += kpart[((size_t)bn * 8 + c) * M_ + m];
        ksum[(size_t)bn * M_ + m] = s;
    }
}

// ---------------- fused per-layer weight prep (+ GMAXU reset)
__global__ __launch_bounds__(256) void prep_kernel(
    const float* __restrict__ wq_l, const float* __restrict__ wk_l,
    const float* __restrict__ wv_l, const float* __restrict__ wo_l,
    const float* __restrict__ wi_l, const float* __restrict__ wo2_l,
    const float* __restrict__ proj_l,
    const float* __restrict__ bq_l, const float* __restrict__ bk_l, const float* __restrict__ bv_l,
    __hip_bfloat16* __restrict__ wqT, __hip_bfloat16* __restrict__ wkT,
    __hip_bfloat16* __restrict__ wvT, __hip_bfloat16* __restrict__ woT,
    __hip_bfloat16* __restrict__ wiT, __hip_bfloat16* __restrict__ wo2T,
    __hip_bfloat16* __restrict__ projb, float* __restrict__ biasq,
    unsigned* __restrict__ gmaxu)
{
    __shared__ float tile[32][33];
    int bid = blockIdx.x;
    if (bid < 6912) {
        const float* src; __hip_bfloat16* dst; int K, N, kt, nt;
        if (bid < 2304) {
            int t = bid / 576, idx = bid % 576;
            src = (t == 0) ? wq_l : (t == 1) ? wk_l : (t == 2) ? wv_l : wo_l;
            dst = (t == 0) ? wqT : (t == 1) ? wkT : (t == 2) ? wvT : woT;
            K = 768; N = 768; kt = idx % 24; nt = idx / 24;
        } else if (bid < 4608) {
            int idx = bid - 2304;
            src = wi_l; dst = wiT; K = 768; N = 3072;
            kt = idx % 24; nt = idx / 24;
        } else {
            int idx = bid - 4608;
            src = wo2_l; dst = wo2T; K = 3072; N = 768;
            kt = idx % 96; nt = idx / 96;
        }
        int k0 = kt * 32, n0 = nt * 32;
        int tx = threadIdx.x & 31, ty = threadIdx.x >> 5;
        #pragma unroll
        for (int i = 0; i < 4; i++)
            tile[ty + i * 8][tx] = src[(size_t)(k0 + ty + i * 8) * N + n0 + tx];
        __syncthreads();
        #pragma unroll
        for (int i = 0; i < 4; i++)
            dst[(size_t)(n0 + ty + i * 8) * K + k0 + tx] = __float2bfloat16(tile[tx][ty + i * 8]);
    } else if (bid < 6976) {
        int i = (bid - 6912) * 256 + threadIdx.x;
        projb[i] = __float2bfloat16(proj_l[i]);
    } else if (bid < 6985) {
        int i = (bid - 6976) * 256 + threadIdx.x;
        if (i < 768) biasq[i] = bq_l[i];
        else if (i < 1536) biasq[i] = bk_l[i - 768];
        else if (i < 2304) biasq[i] = bv_l[i - 1536];
    } else {
        if (threadIdx.x < 24) gmaxu[threadIdx.x] = 0u;
    }
}

// x = LN(word_emb + pos_emb + type_emb); fp32 + bf16 shadow
__global__ __launch_bounds__(256) void embed_ln_kernel(
    const int* __restrict__ ids, const int* __restrict__ tts, const int* __restrict__ pos,
    const float* __restrict__ wemb, const float* __restrict__ pemb, const float* __restrict__ temb,
    const float* __restrict__ g, const float* __restrict__ bb,
    float* __restrict__ out, __hip_bfloat16* __restrict__ outb)
{
    size_t row = blockIdx.x;
    int id = ids[row], tt = tts[row], ps = pos[row];
    const float* w0 = wemb + (size_t)id * H_;
    const float* p0 = pemb + (size_t)ps * H_;
    const float* t0 = temb + (size_t)tt * H_;
    float vals[3], s1 = 0.f, s2 = 0.f;
    #pragma unroll
    for (int i = 0; i < 3; i++) {
        int h = threadIdx.x + i * 256;
        float v = w0[h] + p0[h] + t0[h];
        vals[i] = v; s1 += v; s2 += v * v;
    }
    blockReduceSum2(s1, s2);
    float mu = s1 * (1.0f / H_);
    float var = s2 * (1.0f / H_) - mu * mu;
    float rs = rsqrtf(var + EPS_);
    #pragma unroll
    for (int i = 0; i < 3; i++) {
        int h = threadIdx.x + i * 256;
        float y = (vals[i] - mu) * rs * g[h] + bb[h];
        out[row * H_ + h] = y;
        outb[row * H_ + h] = __float2bfloat16(y);
    }
}

// out = LN(P + Q); fp32 + optional bf16 shadow
__global__ __launch_bounds__(256) void add_ln_kernel(
    const float* __restrict__ P, const float* __restrict__ Q,
    const float* __restrict__ g, const float* __restrict__ bb,
    float* __restrict__ out, __hip_bfloat16* __restrict__ outb)
{
    size_t row = blockIdx.x;
    float vals[3], s1 = 0.f, s2 = 0.f;
    #pragma unroll
    for (int i = 0; i < 3; i++) {
        int h = threadIdx.x + i * 256;
        float v = P[row * H_ + h] + Q[row * H_ + h];
        vals[i] = v; s1 += v; s2 += v * v;
    }
    blockReduceSum2(s1, s2);
    float mu = s1 * (1.0f / H_);
    float var = s2 * (1.0f / H_) - mu * mu;
    float rs = rsqrtf(var + EPS_);
    #pragma unroll
    for (int i = 0; i < 3; i++) {
        int h = threadIdx.x + i * 256;
        float y = (vals[i] - mu) * rs * g[h] + bb[h];
        out[row * H_ + h] = y;
        if (outb) outb[row * H_ + h] = __float2bfloat16(y);
    }
}

// out = LN(p0 + p1 + bias + Q); fp32 + bf16 shadow (FFN2 split-K reduce + LN2)
__global__ __launch_bounds__(256) void add_ln3_kernel(
    const float* __restrict__ planes, const float* __restrict__ bias,
    const float* __restrict__ Q,
    const float* __restrict__ g, const float* __restrict__ bb,
    float* __restrict__ out, __hip_bfloat16* __restrict__ outb)
{
    size_t row = blockIdx.x;
    float vals[3], s1 = 0.f, s2 = 0.f;
    #pragma unroll
    for (int i = 0; i < 3; i++) {
        int h = threadIdx.x + i * 256;
        size_t e = row * H_ + h;
        float v = planes[e] + planes[NXH_ + e] + bias[h] + Q[e];
        vals[i] = v; s1 += v; s2 += v * v;
    }
    blockReduceSum2(s1, s2);
    float mu = s1 * (1.0f / H_);
    float var = s2 * (1.0f / H_) - mu * mu;
    float rs = rsqrtf(var + EPS_);
    #pragma unroll
    for (int i = 0; i < 3; i++) {
        int h = threadIdx.x + i * 256;
        float y = (vals[i] - mu) * rs * g[h] + bb[h];
        out[row * H_ + h] = y;
        outb[row * H_ + h] = __float2bfloat16(y);
    }
}

extern "C" void kernel_launch(void* const* d_in, const int* in_sizes, int n_in,
                              void* d_out, int out_size, void* d_ws, size_t ws_size,
                              hipStream_t stream)
{
    const int* input_ids  = (const int*)d_in[0];
    const int* token_type = (const int*)d_in[1];
    const int* position   = (const int*)d_in[2];
    const int* amask      = (const int*)d_in[3];
    const float* wemb = (const float*)d_in[4];
    const float* pemb = (const float*)d_in[5];
    const float* temb = (const float*)d_in[6];
    const float* elng = (const float*)d_in[7];
    const float* elnb = (const float*)d_in[8];
    const float* wq  = (const float*)d_in[9];
    const float* bq  = (const float*)d_in[10];
    const float* wk  = (const float*)d_in[11];
    const float* bk  = (const float*)d_in[12];
    const float* wv  = (const float*)d_in[13];
    const float* bv  = (const float*)d_in[14];
    const float* wo  = (const float*)d_in[15];
    const float* bo  = (const float*)d_in[16];
    const float* ln1g = (const float*)d_in[17];
    const float* ln1b = (const float*)d_in[18];
    const float* wi  = (const float*)d_in[19];
    const float* bi  = (const float*)d_in[20];
    const float* wo2 = (const float*)d_in[21];
    const float* bo2 = (const float*)d_in[22];
    const float* ln2g = (const float*)d_in[23];
    const float* ln2b = (const float*)d_in[24];
    const float* proj = (const float*)d_in[25];

    float* ws = (float*)d_ws;
    float* X    = ws;                          // 3145728
    float* T2   = X + 3145728;                 // 3145728
    float* BIG  = T2 + 3145728;                // 12582912 (kfeat bf16 / FFN1 out bf16)
    float* U    = BIG + 12582912;              // 6291456 (PART / FFN2 planes)
    __hip_bfloat16* Xb  = (__hip_bfloat16*)(U + 6291456);            // 3145728 el
    __hip_bfloat16* Qb  = (__hip_bfloat16*)((float*)Xb + 1572864);   // Qb|Kb|Vb contiguous
    __hip_bfloat16* Kb  = Qb + 3145728;
    __hip_bfloat16* Vb  = Kb + 3145728;
    __hip_bfloat16* BF1 = Vb + 3145728;                              // 3145728 el
    __hip_bfloat16* WT  = BF1 + 3145728;                             // 7094272 el
    float* kvT_f = (float*)(WT + 7094272);     // kvT bf16 393216 el = 196608 f
    __hip_bfloat16* kvT = (__hip_bfloat16*)kvT_f;
    float* KSUM  = kvT_f + 196608;             // 6144
    float* KPART = KSUM + 6144;                // 49152 used (24*8*256)
    float* RSVD  = KPART + 196608;             // unused
    unsigned* GMAXU = (unsigned*)(RSVD + 98304); // 24 used
    float* QD    = (float*)GMAXU + 64;         // 49152  (KD follows contiguously)
    float* KD    = QD + 49152;                 // 49152
    float* BIASQ = KD + 49152;                 // 2304
    float* T1    = (float*)d_out;              // [4096,768] scratch aliasing output

    __hip_bfloat16* wqT  = WT;                 // packed QKV^T contiguous [2304,768]
    __hip_bfloat16* wkT  = wqT + 589824;
    __hip_bfloat16* wvT  = wkT + 589824;
    __hip_bfloat16* woT  = wvT + 589824;
    __hip_bfloat16* wiT  = woT + 589824;
    __hip_bfloat16* wo2T = wiT + 2359296;
    __hip_bfloat16* projb = wo2T + 2359296;    // 16384 el
    float* PART = U;                           // kv partials (dead after kvred)
    float* PLANES = U;                         // FFN2 split-K planes (2 x NXH_)
    __hip_bfloat16* BIGb = (__hip_bfloat16*)BIG;   // kfeat [49152][256] bf16 / FFN1 out

    embed_ln_kernel<<<BS_, 256, 0, stream>>>(input_ids, token_type, position,
        wemb, pemb, temb, elng, elnb, X, Xb);

    for (int l = 0; l < L_; l++) {
        const float* wq_l = wq + (size_t)l * H_ * NH_ * HD_;
        const float* wk_l = wk + (size_t)l * H_ * NH_ * HD_;
        const float* wv_l = wv + (size_t)l * H_ * NH_ * HD_;
        const float* wo_l = wo + (size_t)l * NH_ * HD_ * H_;
        const float* bq_l = bq + (size_t)l * NH_ * HD_;
        const float* bk_l = bk + (size_t)l * NH_ * HD_;
        const float* bv_l = bv + (size_t)l * NH_ * HD_;
        const float* bo_l = bo + (size_t)l * H_;
        const float* wi_l = wi + (size_t)l * H_ * I_;
        const float* bi_l = bi + (size_t)l * I_;
        const float* wo2_l = wo2 + (size_t)l * I_ * H_;
        const float* bo2_l = bo2 + (size_t)l * H_;
        const float* proj_l = proj + (size_t)l * M_ * HD_;

        // ---- fused weight prep + GMAXU reset ----
        prep_kernel<<<6986, 256, 0, stream>>>(wq_l, wk_l, wv_l, wo_l, wi_l, wo2_l, proj_l,
            bq_l, bk_l, bv_l, wqT, wkT, wvT, woT, wiT, wo2T, projb, BIASQ, GMAXU);

        // ---- fused QKV GEMM -> Qb|Kb|Vb bf16 + qd/kd in epilogue ----
        gemm_pipe3_kernel<0,2><<<dim3(18,32), 256, 0, stream>>>(
            Xb, wqT, BIASQ, (void*)Qb, 768, 768, 768, 768, QD);

        // ---- K path: proj-K (bf16 features + atomic gmax) -> fused k'/kv/ksum ----
        gemm_projk_kernel<<<dim3(2,384), 256, 0, stream>>>(
            Kb, projb, BIGb, 64, 64, 64, 256, DN_, GMAXU);
        kv_fused_kernel<<<dim3(4, B_*NH_, 8), 256, 0, stream>>>(
            BIGb, Vb, KD, GMAXU, amask, PART, KPART);
        kvred_kernel<<<dim3(B_*NH_, HD_+1), 256, 0, stream>>>(PART, kvT, KPART, KSUM);

        // ---- Q path: fully fused proj + rowmax + q' + den + num ----
        qnum_fused_kernel<<<dim3(16, B_*NH_), 512, 0, stream>>>(
            Qb, projb, QD, KSUM, kvT, BF1);

        // ---- attn out proj + LN1 ----
        gemm_pipe3_n64_kernel<<<dim3(12,32), 256, 0, stream>>>(
            BF1, woT, bo_l, T1, 768, 768, 768, 768);
        add_ln_kernel<<<BS_, 256, 0, stream>>>(T1, X, ln1g + (size_t)l*H_, ln1b + (size_t)l*H_, T2, BF1);

        // ---- FFN1 (gelu, bf16 out) ----
        gemm_pipe3_kernel<1,1><<<dim3(24,32), 256, 0, stream>>>(
            BF1, wiT, bi_l, (void*)BIGb, 768, 768, 768, 3072, nullptr);

        // ---- FFN2: split-K x2 128^2 pipe3 -> fp32 planes + fused reduce/LN2 ----
        gemm_pipe3_kernel<0,3><<<dim3(6,32,2), 256, 0, stream>>>(
            BIGb, wo2T, nullptr, nullptr, 1536, 3072, 3072, 768, PLANES);
        float* xout = (l == L_ - 1) ? (float*)d_out : X;
        add_ln3_kernel<<<BS_, 256, 0, stream>>>(PLANES, bo2_l, T2,
            ln2g + (size_t)l*H_, ln2b + (size_t)l*H_, xout, Xb);
    }
}